// Round 2
// baseline (422.527 us; speedup 1.0000x reference)
//
#include <hip/hip_runtime.h>
#include <hip/hip_bf16.h>
#include <cstdint>
#include <cstddef>

#define T_ 512
#define DF 64
#define NPAIR 120
#define STEPW 16
#define BIG_ 1e10f

// softmin constants: exp((m-x)/g) = exp2((m-x)*log2(e)/g); g*ln(2)
#define C1_ 0.28853900817779268f   // log2(e)/5
#define C2_ 3.4657359027997265f    // 5*ln(2)

__device__ __forceinline__ float wred_sum(float v) {
#pragma unroll
  for (int o = 32; o > 0; o >>= 1) v += __shfl_down(v, o);
  return v;  // lane 0 holds the total
}

// ---------------------------------------------------------------------------
// Kernel 1: pairwise sq-dist GEMM, output in anti-diagonal (skewed) layout.
// Dsk[pc][s][j] = D[i][j] with s = i+j.  Block: one 64x64 tile of one pair.
// ---------------------------------------------------------------------------
__global__ __launch_bounds__(256) void gemm_dsk_kernel(
    const float* __restrict__ data, float* __restrict__ dsk, int pair0) {
  __shared__ float Xs[64][65];
  __shared__ float Ys[64][65];
  __shared__ float nrmx[64];
  __shared__ float nrmy[64];

  const int tile = blockIdx.x;   // 0..63 = (bi<<3)|bj
  const int pc = blockIdx.y;     // pair within chunk
  const int p = pair0 + pc;
  const int w = p / 15;
  const int o = p - w * 15;
  const int aidx = w * STEPW;
  const int oidx = aidx + 1 + o;
  const int i0 = (tile >> 3) << 6;
  const int j0 = (tile & 7) << 6;
  const int tid = threadIdx.x;

  const float* Xg = data + (size_t)aidx * (T_ * DF);
  const float* Yg = data + (size_t)oidx * (T_ * DF);

  // stage 64x64 fp32 tiles (K = DF = 64 entirely)
#pragma unroll
  for (int l = 0; l < 4; ++l) {
    int idx = tid + l * 256;  // 0..1023
    int r = idx >> 4;
    int c = idx & 15;
    float4 xv = reinterpret_cast<const float4*>(Xg + (size_t)(i0 + r) * DF)[c];
    float4 yv = reinterpret_cast<const float4*>(Yg + (size_t)(j0 + r) * DF)[c];
    Xs[r][4 * c + 0] = xv.x; Xs[r][4 * c + 1] = xv.y;
    Xs[r][4 * c + 2] = xv.z; Xs[r][4 * c + 3] = xv.w;
    Ys[r][4 * c + 0] = yv.x; Ys[r][4 * c + 1] = yv.y;
    Ys[r][4 * c + 2] = yv.z; Ys[r][4 * c + 3] = yv.w;
  }
  __syncthreads();

  if (tid < 128) {
    int r = tid & 63;
    const float* row = (tid < 64) ? Xs[r] : Ys[r];
    float s = 0.f;
#pragma unroll
    for (int k = 0; k < 64; ++k) s = fmaf(row[k], row[k], s);
    if (tid < 64) nrmx[r] = s; else nrmy[r] = s;
  }
  __syncthreads();

  const int tx = tid & 15;
  const int ty = tid >> 4;
  float acc[4][4];
#pragma unroll
  for (int a = 0; a < 4; ++a)
#pragma unroll
    for (int b = 0; b < 4; ++b) acc[a][b] = 0.f;

#pragma unroll 4
  for (int k = 0; k < 64; ++k) {
    float xr[4], yr[4];
#pragma unroll
    for (int a = 0; a < 4; ++a) xr[a] = Xs[ty * 4 + a][k];
#pragma unroll
    for (int b = 0; b < 4; ++b) yr[b] = Ys[tx * 4 + b][k];
#pragma unroll
    for (int a = 0; a < 4; ++a)
#pragma unroll
      for (int b = 0; b < 4; ++b) acc[a][b] = fmaf(xr[a], yr[b], acc[a][b]);
  }
  __syncthreads();

  // store D tile into LDS with column-rotate swizzle: Xs[ii][(ii+jj)&63]
  // (on a diagonal ii+jj = d the rotated column is constant -> bank = ii+const,
  //  conflict-free diagonal reads; naive layout would be 64-way conflicted)
#pragma unroll
  for (int a = 0; a < 4; ++a)
#pragma unroll
    for (int b = 0; b < 4; ++b) {
      int ii = ty * 4 + a, jj = tx * 4 + b;
      Xs[ii][(ii + jj) & 63] = nrmx[ii] + nrmy[jj] - 2.f * acc[a][b];
    }
  __syncthreads();

  // write diagonals: lanes map to contiguous jj -> coalesced global stores
  float* dskp = dsk + (size_t)pc * (1023 * 512) + (size_t)(i0 + j0) * 512 + j0;
  for (int l = tid; l < 127 * 64; l += 256) {
    int d = l >> 6;
    int t = l & 63;
    int jlo = d > 63 ? d - 63 : 0;
    int jj = jlo + t;
    if (jj <= d && jj < 64) {
      int ii = d - jj;
      dskp[(size_t)d * 512 + jj] = Xs[ii][(ii + jj) & 63];
    }
  }
}

// ---------------------------------------------------------------------------
// Kernel 2: softDTW wavefront. One block per pair, thread j owns column j.
// ---------------------------------------------------------------------------
#define DTW_STEP(S, DV)                                              \
  do {                                                               \
    const int s = (S);                                               \
    if (ln == 63) bnd[s & 1][wv] = myR;                              \
    __syncthreads();                                                 \
    float nb1 = __shfl_up(myR, 1);                                   \
    if (ln == 0 && wv > 0) nb1 = bnd[s & 1][wv - 1];                 \
    const int i = s - j;                                             \
    float left = (j == 0) ? BIG_ : nb1;                              \
    float diag = (j == 0) ? ((i == 0) ? 0.f : BIG_) : nb2;           \
    float up = myR;                                                  \
    float m = fminf(fminf(left, up), diag);                          \
    float e = __builtin_exp2f((m - left) * C1_) +                    \
              __builtin_exp2f((m - up) * C1_) +                      \
              __builtin_exp2f((m - diag) * C1_);                     \
    float rr = (DV) + m - C2_ * __builtin_log2f(e);                  \
    nb2 = nb1;                                                       \
    if (i >= 0 && i < 512) {                                         \
      myR = rr;                                                      \
      if (jmatch && s == starget) dist[p] = rr * invl;               \
    }                                                                \
  } while (0)

__global__ __launch_bounds__(512) void dtw_kernel(
    const float* __restrict__ dsk, const int* __restrict__ lens,
    float* __restrict__ dist, int pair0) {
  const int pc = blockIdx.x;
  const int p = pair0 + pc;
  const int w = p / 15;
  const int o = p - w * 15;
  const int aidx = w * STEPW;
  const int oidx = aidx + 1 + o;
  const int lx = lens[aidx];
  const int ly = lens[oidx];
  const int j = threadIdx.x;
  const int wv = j >> 6;
  const int ln = j & 63;

  __shared__ float bnd[2][8];

  const float* dp = dsk + (size_t)pc * (1023 * 512) + j;
  const bool jmatch = (j == ly - 1);
  const int starget = (lx - 1) + (ly - 1);
  const float invl = 1.f / (float)(lx + ly);

  float myR = BIG_;                      // own R from previous step (row above)
  float nb2 = (j == 0) ? 0.f : BIG_;     // neighbor R from two steps ago (diag)

  // software prefetch 8 steps deep (named regs; runtime-indexed arrays spill)
  float d0 = dp[(size_t)0 * 512];
  float d1 = dp[(size_t)1 * 512];
  float d2 = dp[(size_t)2 * 512];
  float d3 = dp[(size_t)3 * 512];
  float d4 = dp[(size_t)4 * 512];
  float d5 = dp[(size_t)5 * 512];
  float d6 = dp[(size_t)6 * 512];
  float d7 = dp[(size_t)7 * 512];

  for (int s0 = 0; s0 < 1024; s0 += 8) {
    int n0 = s0 + 8 < 1022 ? s0 + 8 : 1022;
    int n1 = s0 + 9 < 1022 ? s0 + 9 : 1022;
    int n2 = s0 + 10 < 1022 ? s0 + 10 : 1022;
    int n3 = s0 + 11 < 1022 ? s0 + 11 : 1022;
    int n4 = s0 + 12 < 1022 ? s0 + 12 : 1022;
    int n5 = s0 + 13 < 1022 ? s0 + 13 : 1022;
    int n6 = s0 + 14 < 1022 ? s0 + 14 : 1022;
    int n7 = s0 + 15 < 1022 ? s0 + 15 : 1022;
    DTW_STEP(s0 + 0, d0); d0 = dp[(size_t)n0 * 512];
    DTW_STEP(s0 + 1, d1); d1 = dp[(size_t)n1 * 512];
    DTW_STEP(s0 + 2, d2); d2 = dp[(size_t)n2 * 512];
    DTW_STEP(s0 + 3, d3); d3 = dp[(size_t)n3 * 512];
    DTW_STEP(s0 + 4, d4); d4 = dp[(size_t)n4 * 512];
    DTW_STEP(s0 + 5, d5); d5 = dp[(size_t)n5 * 512];
    DTW_STEP(s0 + 6, d6); d6 = dp[(size_t)n6 * 512];
    DTW_STEP(s0 + 7, d7); d7 = dp[(size_t)n7 * 512];
  }
}

// ---------------------------------------------------------------------------
// Kernel 3: MMD pairwise per-feature L2 (upper triangle, mirrored)
// ---------------------------------------------------------------------------
__global__ __launch_bounds__(64) void mmd_l2_kernel(
    const float* __restrict__ data, float* __restrict__ l2buf,
    float* __restrict__ bwpart) {
  int b = blockIdx.x;  // 0..252 upper-tri (incl diag) index
  int u = 0, rem = b;
  while (rem >= 22 - u) { rem -= 22 - u; ++u; }
  int v = u + rem;
  int f = threadIdx.x;
  float s = 0.f;
  if (u != v) {
    int iu = u < 11 ? u : u + 5;
    int iv = v < 11 ? v : v + 5;
    const float* A = data + (size_t)iu * (T_ * DF) + f;
    const float* B = data + (size_t)iv * (T_ * DF) + f;
#pragma unroll 8
    for (int t = 0; t < T_; ++t) {
      float dd = A[(size_t)t * DF] - B[(size_t)t * DF];
      s = fmaf(dd, dd, s);
    }
  }
  l2buf[(size_t)(u * 22 + v) * 64 + f] = s;
  l2buf[(size_t)(v * 22 + u) * 64 + f] = s;
  float tot = wred_sum(s);
  if (f == 0) bwpart[b] = 2.f * tot;  // diag contributes exactly 0
}

// ---------------------------------------------------------------------------
// Kernel 4: MMD kernel sums per (a,c) of the 11x11 grid
// ---------------------------------------------------------------------------
__global__ __launch_bounds__(64) void mmd_k_kernel(
    const float* __restrict__ l2buf, const float* __restrict__ bwpart,
    float* __restrict__ mmdpart) {
  int b = blockIdx.x;  // 0..120
  int a = b / 11, c = b - a * 11;
  int f = threadIdx.x;
  float bs = 0.f;
  for (int k2 = f; k2 < 253; k2 += 64) bs += bwpart[k2];
  bs = wred_sum(bs);
  float bw = __shfl(bs, 0) * (1.f / (462.f * 4.f));  // /(n^2-n)/KMUL^(KNUM//2)
  float xx = l2buf[(size_t)(a * 22 + c) * 64 + f];
  float yy = l2buf[(size_t)((11 + a) * 22 + (11 + c)) * 64 + f];
  float xy = l2buf[(size_t)(a * 22 + (11 + c)) * 64 + f];
  float yx = l2buf[(size_t)((11 + a) * 22 + c) * 64 + f];
  float term = 0.f;
  float ib = 1.f / bw;
#pragma unroll
  for (int i = 0; i < 5; ++i) {
    term += expf(-xx * ib) + expf(-yy * ib) - expf(-xy * ib) - expf(-yx * ib);
    ib *= 0.5f;
  }
  float tt = wred_sum(term);
  if (f == 0) mmdpart[b] = tt;
}

// ---------------------------------------------------------------------------
// Kernel 5: finalize — triplet loss + variance + MMD mean -> out[0]
// ---------------------------------------------------------------------------
__global__ __launch_bounds__(64) void finalize_kernel(
    const float* __restrict__ dist, const float* __restrict__ mmdpart,
    float* __restrict__ out) {
  int lane = threadIdx.x;
  float lv_po = 0.f;
  float dg[5];
#pragma unroll
  for (int g = 0; g < 5; ++g) dg[g] = 0.f;
  if (lane < 8) {
    const float* dr = dist + lane * 15;
    float dn[10];
#pragma unroll
    for (int g = 0; g < 5; ++g) dg[g] = dr[g];
#pragma unroll
    for (int k = 0; k < 10; ++k) dn[k] = dr[5 + k];
    float s1 = 0.f, s2 = 0.f;
    int nz = 0;
#pragma unroll
    for (int g = 0; g < 5; ++g) {
#pragma unroll
      for (int k = 0; k < 5; ++k) {
        float v2 = dg[g] + 1.0f - dn[k];
        if (v2 > 0.f) { s1 += v2; ++nz; }
      }
#pragma unroll
      for (int k = 5; k < 10; ++k) {
        float v2 = dg[g] + 1.0f - dn[k];
        if (v2 > 0.f) { s2 += v2; ++nz; }
      }
    }
    float only_pos = (dg[0] + dg[1] + dg[2] + dg[3] + dg[4]) * 0.002f;
    float lv = (s1 * 0.7f + s2 * 0.3f) / (float)(nz + 1);
    lv_po = lv + only_pos;
  }
  float tl = wred_sum(lv_po);
  tl = __shfl(tl, 0);

  // two-pass ddof=1 variance over the 40 dg values
  float psum = dg[0] + dg[1] + dg[2] + dg[3] + dg[4];
  float tsum = wred_sum(psum);
  float mean = __shfl(tsum, 0) * (1.f / 40.f);
  float pdev = 0.f;
  if (lane < 8) {
#pragma unroll
    for (int g = 0; g < 5; ++g) {
      float dd = dg[g] - mean;
      pdev = fmaf(dd, dd, pdev);
    }
  }
  float tdev = wred_sum(pdev);
  tdev = __shfl(tdev, 0);

  float msum = 0.f;
  for (int k2 = lane; k2 < 121; k2 += 64) msum += mmdpart[k2];
  float mt = wred_sum(msum);

  if (lane == 0) {
    float total_loss = tl * (1.f / 8.f);
    float var_g = (tdev / 39.f) * 0.1f;
    float mmd = mt * (1.f / 7744.f);
    out[0] = total_loss + mmd + var_g;
  }
}

__global__ __launch_bounds__(64) void zero_out_kernel(float* __restrict__ out,
                                                      int n) {
  int i = blockIdx.x * 64 + threadIdx.x;
  if (i < n) out[i] = 0.f;
}

// ---------------------------------------------------------------------------
extern "C" void kernel_launch(void* const* d_in, const int* in_sizes, int n_in,
                              void* d_out, int out_size, void* d_ws,
                              size_t ws_size, hipStream_t stream) {
  const float* data = (const float*)d_in[0];
  const int* lens = (const int*)d_in[1];
  float* out = (float*)d_out;
  char* ws = (char*)d_ws;

  const size_t HDR = 131072;  // dist/bwpart/mmdpart/l2buf region
  const size_t per_pair = (size_t)1023 * 512 * sizeof(float);

  // Strict workspace guard: never touch bytes beyond ws_size.
  if (ws_size < HDR + per_pair) {
    zero_out_kernel<<<dim3((out_size + 63) / 64), 64, 0, stream>>>(out,
                                                                   out_size);
    return;
  }

  float* dist = (float*)(ws + 0);        // 120 floats
  float* bwpart = (float*)(ws + 1024);   // 253 floats
  float* mmdpart = (float*)(ws + 3072);  // 121 floats
  float* l2buf = (float*)(ws + 4096);    // 22*22*64 floats = 123904 B
  float* dsk = (float*)(ws + HDR);

  size_t avail = ws_size - HDR;
  int PC = (int)(avail / per_pair);
  if (PC > NPAIR) PC = NPAIR;

  for (int p0 = 0; p0 < NPAIR; p0 += PC) {
    int pc = (NPAIR - p0) < PC ? (NPAIR - p0) : PC;
    gemm_dsk_kernel<<<dim3(64, pc), 256, 0, stream>>>(data, dsk, p0);
    dtw_kernel<<<dim3(pc), 512, 0, stream>>>(dsk, lens, dist, p0);
  }
  mmd_l2_kernel<<<dim3(253), 64, 0, stream>>>(data, l2buf, bwpart);
  mmd_k_kernel<<<dim3(121), 64, 0, stream>>>(l2buf, bwpart, mmdpart);
  finalize_kernel<<<dim3(1), 64, 0, stream>>>(dist, mmdpart, out);
}